// Round 9
// baseline (1656.423 us; speedup 1.0000x reference)
//
#include <hip/hip_runtime.h>
#include <cstdint>

typedef __bf16 bf16;
typedef __attribute__((ext_vector_type(4))) __bf16 bf16x4;
typedef __attribute__((ext_vector_type(8))) __bf16 bf16x8;
typedef __attribute__((ext_vector_type(4))) float f32x4;
typedef __attribute__((ext_vector_type(2))) float f32x2;

// async 16B/lane global->LDS (dest = wave-uniform base + lane*16)
#define ASYNC16(gptr, lptr)                                                      \
  __builtin_amdgcn_global_load_lds(                                              \
      (const __attribute__((address_space(1))) unsigned int*)(gptr),             \
      (__attribute__((address_space(3))) unsigned int*)(lptr), 16, 0, 0)

// ---------------------------------------------------------------------------
// C[M,N] = A[M,K] * BT[N,K]^T (bf16 in, fp32 acc). BK = NSUB*32 staged as NSUB
// 32-k sub-tiles per barrier pair (NSUB=4 halves barrier count vs NSUB=2 at
// K=768: 12 drains instead of 24, 32 MFMA per drain on 64x64 tiles).
// RESMODE: 0 none, 1 fp32 residual, 3 recompute-LN residual:
//   v += (res[idx]-mean[row])*rstd[row]*lng[col]+lnb[col].
// OUTB: bf16 store. VTOUT: QKV GEMM dual-stores V cols transposed to vt.
// ---------------------------------------------------------------------------
template <int BM, int BN, int NSUB, bool BIAS, bool RELU, int RESMODE, bool OUTB,
          bool VTOUT, int MINW>
__global__ __launch_bounds__(256, MINW) void gemm_bt(
    const bf16* __restrict__ A, const bf16* __restrict__ B, void* __restrict__ C,
    const float* __restrict__ bias, const float* __restrict__ res,
    const f32x2* __restrict__ stats, const float* __restrict__ lng,
    const float* __restrict__ lnb, bf16* __restrict__ vt, int K,
    int lda, int ldb, int ldc, int bdiv, long sA1, long sA2, long sB1, long sB2,
    long sC1, long sC2, float scale)
{
  constexpr int FM = BM / 32, FN = BN / 32;
  constexpr int CALLS_A = BM / 64, CALLS_B = BN / 64;   // per 32-k sub-tile
  __shared__ __align__(16) bf16 As[NSUB * BM * 32];
  __shared__ __align__(16) bf16 Bs[NSUB * BN * 32];
  const int tid = threadIdx.x;
  const int wave = tid >> 6, lane = tid & 63;
  const int zb = blockIdx.z / bdiv, zh = blockIdx.z % bdiv;
  const bf16* Ab = A + zb * sA1 + zh * sA2 + (long)blockIdx.y * BM * lda;
  const bf16* Bb = B + zb * sB1 + zh * sB2 + (long)blockIdx.x * BN * ldb;
  const int rA = lane >> 2, kA = (lane & 3) * 8;   // 1KB chunk = 16 rows x 64B
  const int wm = wave >> 1, wn = wave & 1;
  const int mBase = wm * (BM / 2) + (lane & 15);
  const int nBase = wn * (BN / 2) + (lane & 15);
  const int kOff = (lane >> 4) * 8;

  f32x4 acc[FM][FN] = {};

  for (int k0 = 0; k0 < K; k0 += NSUB * 32) {
#pragma unroll
    for (int hh = 0; hh < NSUB; ++hh) {
      const int kh = k0 + hh * 32;
#pragma unroll
      for (int c = 0; c < CALLS_A; ++c) {
        const int cb = (wave * CALLS_A + c) << 10;
        ASYNC16(Ab + (long)((cb >> 6) + rA) * lda + kh + kA,
                ((char*)As) + hh * (BM * 64) + cb);
      }
#pragma unroll
      for (int c = 0; c < CALLS_B; ++c) {
        const int cb = (wave * CALLS_B + c) << 10;
        ASYNC16(Bb + (long)((cb >> 6) + rA) * ldb + kh + kA,
                ((char*)Bs) + hh * (BN * 64) + cb);
      }
    }
    __syncthreads();
#pragma unroll
    for (int t = 0; t < NSUB; ++t) {
      const bf16* Asub = As + t * BM * 32;
      const bf16* Bsub = Bs + t * BN * 32;
      bf16x8 af[FM], bfr[FN];
#pragma unroll
      for (int i = 0; i < FM; ++i)
        af[i] = *(const bf16x8*)&Asub[(mBase + i * 16) * 32 + kOff];
#pragma unroll
      for (int j = 0; j < FN; ++j)
        bfr[j] = *(const bf16x8*)&Bsub[(nBase + j * 16) * 32 + kOff];
#pragma unroll
      for (int i = 0; i < FM; ++i)
#pragma unroll
        for (int j = 0; j < FN; ++j)
          acc[i][j] = __builtin_amdgcn_mfma_f32_16x16x32_bf16(af[i], bfr[j], acc[i][j], 0, 0, 0);
    }
    __syncthreads();
  }

  // C/D frag: col = lane&15, row = (lane>>4)*4 + r
  const long cBase = zb * sC1 + zh * sC2;
  const int rowB = blockIdx.y * BM + wm * (BM / 2) + ((lane >> 4) << 2);
  const int colB = blockIdx.x * BN + wn * (BN / 2) + (lane & 15);
#pragma unroll
  for (int i = 0; i < FM; ++i) {
    const int row0 = rowB + i * 16;
#pragma unroll
    for (int j = 0; j < FN; ++j) {
      const int col = colB + j * 16;
      float bv = 0.f;
      if constexpr (BIAS) bv = bias[col];
      float gv = 0.f, lv = 0.f;
      if constexpr (RESMODE == 3) { gv = lng[col]; lv = lnb[col]; }
      bf16x4 pk;
#pragma unroll
      for (int r = 0; r < 4; ++r) {
        const int row = row0 + r;
        float v = acc[i][j][r] * scale + bv;
        if constexpr (RELU) v = fmaxf(v, 0.f);
        const long idx = cBase + (long)row * ldc + col;
        if constexpr (RESMODE == 1) v += res[idx];
        if constexpr (RESMODE == 3) {
          const f32x2 st = stats[row];
          v += (res[idx] - st.x) * st.y * gv + lv;
        }
        if constexpr (OUTB) ((bf16*)C)[idx] = (bf16)v;
        else                ((float*)C)[idx] = v;
        if constexpr (VTOUT) pk[r] = (bf16)v;
      }
      if constexpr (VTOUT) {
        if (col >= 1536) {   // V columns: also store transposed
          const int cc = col - 1536;
          const int h = cc >> 6, d = cc & 63;
          const int b = row0 >> 9, s = row0 & 511;
          *(bf16x4*)&vt[(((long)(b * 12 + h) * 64 + d) << 9) + s] = pk;
        }
      }
    }
  }
}

// ---------------------------------------------------------------------------
// Fused attention, 512 threads (8 waves = 2 row-groups x 4 col-waves).
// ---------------------------------------------------------------------------
__global__ __launch_bounds__(512, 1) void fattn(
    const bf16* __restrict__ qkv, const bf16* __restrict__ vT,
    bf16* __restrict__ ctx)
{
  __shared__ __align__(16) bf16 Qs[64 * 64];      //  8 KB
  __shared__ __align__(16) bf16 KVs[512 * 64];    // 64 KB (K ph1, V ph3)
  __shared__ __align__(16) bf16 Ps[64 * 520];     // 65 KB
  __shared__ float sm[64 * 4];
  __shared__ float ssum[64 * 4];

  const int tid = threadIdx.x, wave = tid >> 6, lane = tid & 63;
  const int wg = wave >> 2, wc = wave & 3;
  const int bh = blockIdx.y;
  const int b = bh / 12, h = bh % 12;
  const int q0 = blockIdx.x * 64;
  const bf16* Qg = qkv + (long)(b * 512 + q0) * 2304 + h * 64;
  const bf16* Kg = qkv + (long)(b * 512) * 2304 + 768 + h * 64;
  const bf16* Vg = vT + (long)bh * 32768;

  const int rq = lane >> 3;                       // row within 1KB chunk
  const int kx = (((lane & 7) ^ rq) << 3);        // XOR-swizzled k-offset
  ASYNC16(Qg + (long)(wave * 8 + rq) * 2304 + kx, ((char*)Qs) + (wave << 10));
#pragma unroll
  for (int c = 0; c < 8; ++c) {                   // K: 64KB, 8 chunks/wave
    const int cb = (wave * 8 + c) << 10;
    ASYNC16(Kg + (long)((cb >> 7) + rq) * 2304 + kx, ((char*)KVs) + cb);
  }
  __syncthreads();

  const int m0 = lane & 15, q = lane >> 4;
  const int sw = (m0 & 7);                        // read-side swizzle key
  f32x4 acc[2][8] = {};
#pragma unroll
  for (int t = 0; t < 2; ++t) {
    const int ch = ((t * 4 + q) ^ sw) << 3;
    bf16x8 af[2];
#pragma unroll
    for (int i = 0; i < 2; ++i)
      af[i] = *(const bf16x8*)&Qs[(wg * 32 + i * 16 + m0) * 64 + ch];
#pragma unroll
    for (int j = 0; j < 8; ++j) {
      bf16x8 bf = *(const bf16x8*)&KVs[(wc * 128 + j * 16 + m0) * 64 + ch];
#pragma unroll
      for (int i = 0; i < 2; ++i)
        acc[i][j] = __builtin_amdgcn_mfma_f32_16x16x32_bf16(af[i], bf, acc[i][j], 0, 0, 0);
    }
  }

#pragma unroll
  for (int i = 0; i < 2; ++i)
#pragma unroll
    for (int r = 0; r < 4; ++r) {
      float m = acc[i][0][r];
#pragma unroll
      for (int j = 1; j < 8; ++j) m = fmaxf(m, acc[i][j][r]);
#pragma unroll
      for (int msk = 1; msk < 16; msk <<= 1) m = fmaxf(m, __shfl_xor(m, msk));
      if (m0 == 0) sm[(wg * 32 + i * 16 + q * 4 + r) * 4 + wc] = m;
    }
  __syncthreads();   // K reads done; sm visible

  {  // V loads into KVs (in flight during softmax)
#pragma unroll
    for (int c = 0; c < 8; ++c) {
      const int d = wave * 8 + c;
      const int cb = (wave * 8 + c) << 10;
      ASYNC16(Vg + (long)d * 512 + ((lane ^ c) << 3), ((char*)KVs) + cb);
    }
  }

  const float SCL = 0.125f;
#pragma unroll
  for (int i = 0; i < 2; ++i)
#pragma unroll
    for (int r = 0; r < 4; ++r) {
      const int row = wg * 32 + i * 16 + q * 4 + r;
      f32x4 mv = *(const f32x4*)&sm[row * 4];
      const float M = fmaxf(fmaxf(mv[0], mv[1]), fmaxf(mv[2], mv[3])) * SCL;
      float s = 0.f;
#pragma unroll
      for (int j = 0; j < 8; ++j) {
        const float p = __expf(acc[i][j][r] * SCL - M);
        s += p;
        Ps[row * 520 + wc * 128 + j * 16 + m0] = (bf16)p;
      }
#pragma unroll
      for (int msk = 1; msk < 16; msk <<= 1) s += __shfl_xor(s, msk);
      if (m0 == 0) ssum[row * 4 + wc] = s;
    }
  __syncthreads();   // drains V vmcnt + Ps/ssum writes

  f32x4 cacc[2] = {};
#pragma unroll
  for (int t = 0; t < 16; ++t) {
    const int ch = ((t * 4 + q) ^ sw) << 3;
    bf16x8 bf = *(const bf16x8*)&KVs[(wc * 16 + m0) * 512 + ch];
#pragma unroll
    for (int i = 0; i < 2; ++i) {
      bf16x8 af = *(const bf16x8*)&Ps[(wg * 32 + i * 16 + m0) * 520 + t * 32 + q * 8];
      cacc[i] = __builtin_amdgcn_mfma_f32_16x16x32_bf16(af, bf, cacc[i], 0, 0, 0);
    }
  }
  const long cbase = (long)(b * 512 + q0) * 768 + h * 64;
  const int col = wc * 16 + m0;
#pragma unroll
  for (int i = 0; i < 2; ++i)
#pragma unroll
    for (int r = 0; r < 4; ++r) {
      const int row = wg * 32 + i * 16 + q * 4 + r;
      f32x4 sv = *(const f32x4*)&ssum[row * 4];
      const float inv = 1.f / (sv[0] + sv[1] + sv[2] + sv[3]);
      ctx[cbase + (long)row * 768 + col] = (bf16)(cacc[i][r] * inv);
    }
}

// ---------------------------------------------------------------------------
// Register-transpose weight prep (no LDS, no barriers, no bank conflicts).
// ---------------------------------------------------------------------------
__global__ __launch_bounds__(256) void wprep(
    const float* __restrict__ Wq, const float* __restrict__ Wk,
    const float* __restrict__ Wv, const float* __restrict__ Wo,
    const float* __restrict__ W2, bf16* __restrict__ Tqkv, bf16* __restrict__ To,
    bf16* __restrict__ T2)
{
  const int l = blockIdx.z / 5, t = blockIdx.z % 5;
  const float* W = (t == 0) ? Wq : (t == 1) ? Wk : (t == 2) ? Wv : (t == 3) ? Wo : W2;
  W += (long)l * 589824;
  const int lane = threadIdx.x & 63, wave = threadIdx.x >> 6;
  const int km = lane & 7, nm = lane >> 3;
  const int kk = blockIdx.x * 64 + km * 8;
  const int nn = blockIdx.y * 256 + wave * 64 + nm * 8;

  f32x4 a[8][2];
#pragma unroll
  for (int j = 0; j < 8; ++j) {
    const float* src = W + (long)(kk + j) * 768 + nn;
    a[j][0] = *(const f32x4*)src;
    a[j][1] = *(const f32x4*)(src + 4);
  }

  bf16* dstBase;
  if (t < 3)       dstBase = Tqkv + (long)l * 2304 * 768 + (long)t * 768 * 768;
  else if (t == 3) dstBase = To + (long)l * 589824;
  else             dstBase = T2 + (long)l * 589824;

#pragma unroll
  for (int r = 0; r < 8; ++r) {
    bf16x8 o;
#pragma unroll
    for (int j = 0; j < 8; ++j)
      o[j] = (bf16)(r < 4 ? a[j][0][r] : a[j][1][r - 4]);
    *(bf16x8*)&dstBase[(long)(nn + r) * 768 + kk] = o;
  }
}

__global__ void bias_concat(const float* __restrict__ bq, const float* __restrict__ bk,
                            const float* __restrict__ bv, float* __restrict__ o)
{
  const int i = blockIdx.x * 256 + threadIdx.x;
  if (i >= 12 * 2304) return;
  const int l = i / 2304, n = i % 2304;
  o[i] = (n < 768) ? bq[l * 768 + n] : (n < 1536) ? bk[l * 768 + n - 768] : bv[l * 768 + n - 1536];
}

__global__ void xconv(const float* __restrict__ x, bf16* __restrict__ xb)
{
  const long i = (long)blockIdx.x * 256 + threadIdx.x;
  xb[i] = (bf16)x[i];
}

// one block per 768-elem row; fp32 in -> bf16 out + per-row (mean,rstd) stats
// (+ optional fp32 out for the final layer)
__global__ __launch_bounds__(256) void layernorm_k(
    const float* __restrict__ in, const float* __restrict__ g,
    const float* __restrict__ b, bf16* __restrict__ outb,
    f32x2* __restrict__ stats, float* __restrict__ outf)
{
  const long row = blockIdx.x;
  const int tid = threadIdx.x;
  const float* xr = in + row * 768;
  const float v0 = xr[tid], v1 = xr[tid + 256], v2 = xr[tid + 512];
  float s = v0 + v1 + v2;
  float qv = v0 * v0 + v1 * v1 + v2 * v2;
#pragma unroll
  for (int o = 32; o > 0; o >>= 1) { s += __shfl_down(s, o); qv += __shfl_down(qv, o); }
  __shared__ float rs[4], rq[4];
  const int wave = tid >> 6, lane = tid & 63;
  if (lane == 0) { rs[wave] = s; rq[wave] = qv; }
  __syncthreads();
  const float st = rs[0] + rs[1] + rs[2] + rs[3];
  const float qt = rq[0] + rq[1] + rq[2] + rq[3];
  const float mean = st * (1.f / 768.f);
  float var = qt * (1.f / 768.f) - mean * mean;
  var = fmaxf(var, 0.f);
  const float rstd = rsqrtf(var + 1e-12f);
  if (tid == 0) { f32x2 sv; sv.x = mean; sv.y = rstd; stats[row] = sv; }
  const float y0 = (v0 - mean) * rstd * g[tid] + b[tid];
  const float y1 = (v1 - mean) * rstd * g[tid + 256] + b[tid + 256];
  const float y2 = (v2 - mean) * rstd * g[tid + 512] + b[tid + 512];
  bf16* ob = outb + row * 768;
  ob[tid] = (bf16)y0; ob[tid + 256] = (bf16)y1; ob[tid + 512] = (bf16)y2;
  if (outf) {
    float* of = outf + row * 768;
    of[tid] = y0; of[tid + 256] = y1; of[tid + 512] = y2;
  }
}

// ---------------------------------------------------------------------------
extern "C" void kernel_launch(void* const* d_in, const int* in_sizes, int n_in,
                              void* d_out, int out_size, void* d_ws, size_t ws_size,
                              hipStream_t stream)
{
  const float* x   = (const float*)d_in[0];
  const float* Wq  = (const float*)d_in[1];
  const float* bq  = (const float*)d_in[2];
  const float* Wk  = (const float*)d_in[3];
  const float* bk  = (const float*)d_in[4];
  const float* Wv  = (const float*)d_in[5];
  const float* bv  = (const float*)d_in[6];
  const float* Wo  = (const float*)d_in[7];
  const float* bo  = (const float*)d_in[8];
  const float* g1  = (const float*)d_in[9];
  const float* be1 = (const float*)d_in[10];
  const float* W2  = (const float*)d_in[11];
  const float* b2  = (const float*)d_in[12];
  const float* g2  = (const float*)d_in[13];
  const float* be2 = (const float*)d_in[14];
  (void)in_sizes; (void)n_in; (void)out_size; (void)ws_size;

  char* ws = (char*)d_ws;
  size_t off = 0;
  auto alloc = [&](size_t bytes) {
    void* p = ws + off;
    off = (off + bytes + 255) & ~(size_t)255;
    return p;
  };
  bf16*  wTqkv  = (bf16*)alloc(12L * 2304 * 768 * 2);
  bf16*  wTo    = (bf16*)alloc(12L * 768 * 768 * 2);
  bf16*  wT2    = (bf16*)alloc(12L * 768 * 768 * 2);
  float* bqkv   = (float*)alloc(12L * 2304 * 4);
  bf16*  xb     = (bf16*)alloc(4096L * 768 * 2);
  bf16*  qkv    = (bf16*)alloc(4096L * 2304 * 2);
  bf16*  vT     = (bf16*)alloc(96L * 64 * 512 * 2);
  bf16*  ctx    = (bf16*)alloc(4096L * 768 * 2);
  float* res1   = (float*)alloc(4096L * 768 * 4);
  bf16*  out1b  = (bf16*)alloc(4096L * 768 * 2);
  bf16*  h1b    = (bf16*)alloc(4096L * 768 * 2);
  float* res2   = (float*)alloc(4096L * 768 * 4);
  f32x2* stats1 = (f32x2*)alloc(4096L * 8);
  f32x2* stats2 = (f32x2*)alloc(4096L * 8);

  wprep<<<dim3(12, 3, 60), 256, 0, stream>>>(Wq, Wk, Wv, Wo, W2, wTqkv, wTo, wT2);
  bias_concat<<<dim3(108), 256, 0, stream>>>(bq, bk, bv, bqkv);
  xconv<<<dim3(12288), 256, 0, stream>>>(x, xb);

  for (int l = 0; l < 12; ++l) {
    const bf16* wq_l   = wTqkv + (long)l * 2304 * 768;
    const bf16* wo_l   = wTo + (long)l * 589824;
    const bf16* w2_l   = wT2 + (long)l * 589824;
    const float* bqk_l = bqkv + l * 2304;

    // QKV: [4096,768] x [768,2304] -> qkv bf16 (+bias) + vT dual-store for V
    gemm_bt<128, 64, 2, true, false, 0, true, true, 5><<<dim3(36, 32, 1), 256, 0, stream>>>(
        xb, wq_l, qkv, bqk_l, nullptr, nullptr, nullptr, nullptr, vT, 768,
        768, 768, 2304, 1, 0, 0, 0, 0, 0, 0, 1.f);
    // fused attention -> ctx [B,S,H] bf16
    fattn<<<dim3(8, 96), 512, 0, stream>>>(qkv, vT, ctx);
    // attn out projection + residual -> res1 fp32  (BK=128: 6 iters, 12 drains)
    if (l == 0) {
      gemm_bt<64, 64, 4, true, false, 1, false, false, 4><<<dim3(12, 64, 1), 256, 0, stream>>>(
          ctx, wo_l, res1, bo, x, nullptr, nullptr, nullptr, nullptr, 768,
          768, 768, 768, 1, 0, 0, 0, 0, 0, 0, 1.f);
    } else {
      gemm_bt<64, 64, 4, true, false, 3, false, false, 4><<<dim3(12, 64, 1), 256, 0, stream>>>(
          ctx, wo_l, res1, bo + l * 768, res2, stats2,
          g2 + (l - 1) * 768, be2 + (l - 1) * 768, nullptr, 768,
          768, 768, 768, 1, 0, 0, 0, 0, 0, 0, 1.f);
    }
    layernorm_k<<<dim3(4096), 256, 0, stream>>>(res1, g1 + l * 768, be1 + l * 768,
                                                out1b, stats1, nullptr);
    // FF1: relu(out1 @ W2 + b2) -> h1b bf16
    gemm_bt<64, 64, 4, true, true, 0, true, false, 4><<<dim3(12, 64, 1), 256, 0, stream>>>(
        out1b, w2_l, h1b, b2 + l * 768, nullptr, nullptr, nullptr, nullptr, nullptr, 768,
        768, 768, 768, 1, 0, 0, 0, 0, 0, 0, 1.f);
    // FF2: LN1(res1) + relu(h @ W2 + b2) -> res2 fp32
    gemm_bt<64, 64, 4, true, true, 3, false, false, 4><<<dim3(12, 64, 1), 256, 0, stream>>>(
        h1b, w2_l, res2, b2 + l * 768, res1, stats1,
        g1 + l * 768, be1 + l * 768, nullptr, 768,
        768, 768, 768, 1, 0, 0, 0, 0, 0, 0, 1.f);
    layernorm_k<<<dim3(4096), 256, 0, stream>>>(res2, g2 + l * 768, be2 + l * 768,
                                                xb, stats2, (l == 11) ? (float*)d_out : nullptr);
  }
}